// Round 16
// baseline (398.515 us; speedup 1.0000x reference)
//
#include <hip/hip_runtime.h>

#define NPTS 16384
#define DH 256
#define PH 4096
#define D2 512
#define LDA 40   // A-tile padded row stride (halfs): 80 B rows -> 2-way banks (free)

typedef _Float16 f16;
typedef _Float16 f16x4 __attribute__((ext_vector_type(4)));
typedef _Float16 f16x8 __attribute__((ext_vector_type(8)));
typedef float f32x4 __attribute__((ext_vector_type(4)));

// Static device scratch; all buffers fully rewritten before use each call.
// Globals are LINEAR; B-side LDS swizzle phi(r)=(r+(r>>2))&3 is applied in the
// per-lane gload SOURCE address (m173) and the frag-read slot index.
__device__ f16   g_eAt[D2][NPTS];       // 16 MB: eA^T fp16 [d][n]
__device__ f16   g_Tt[4][D2][2*PH];     // 64 MB: T K-split partials
__device__ f16   g_Ts[D2][2*PH];        //  8 MB: T summed, [d][2q+cs] linear
__device__ float g_G[2][NPTS][D2];      // 64 MB: G K-split partials

__device__ __forceinline__ void gload16(const void* g, void* l) {
    __builtin_amdgcn_global_load_lds((const __attribute__((address_space(1))) void*)g,
                                     (__attribute__((address_space(3))) void*)l, 16, 0, 0);
}

__device__ __forceinline__ void fsincos(float x, float* s, float* c) {
    *s = __sinf(x); *c = __cosf(x);
}

// ---------------------------------------------------------------------------
// eA^T precompute (linear): g_eAt[d][n]=cos(alpha), g_eAt[256+d][n]=sin.
// ---------------------------------------------------------------------------
__global__ __launch_bounds__(256) void ker_pre(const float* __restrict__ pts,
                                               const float* __restrict__ A) {
    const int dd = blockIdx.x;           // 0..255
    const int t  = threadIdx.x;          // 64-col chunk c = t
    const float a0 = A[dd], a1 = A[DH + dd], a2 = A[2*DH + dd];
    f16* rowc = &g_eAt[dd][t*64];
    f16* rows = &g_eAt[DH + dd][t*64];
    #pragma unroll
    for (int s = 0; s < 8; ++s) {
        const int nb = t*64 + 8*s;
        f16x8 vc, vs;
        #pragma unroll
        for (int i = 0; i < 8; ++i) {
            const float* pr = pts + (size_t)(nb + i)*3;
            float sn, cs_; fsincos(pr[0]*a0 + pr[1]*a1 + pr[2]*a2, &sn, &cs_);
            vc[i] = (f16)cs_; vs[i] = (f16)sn;
        }
        *(f16x8*)(rowc + 8*s) = vc;
        *(f16x8*)(rows + 8*s) = vs;
    }
}

// ---------------------------------------------------------------------------
// GEMM1: T = eB^T eA. Block: M=128 (64 q x {cos,sin}), N=256 d, BK=32 n.
// Grid (64,2,4) = 512 blocks = 2/CU. 8 waves (2M x 4N), wave-tile 64x64.
// R16 schedule: B ring-3 prefetch (tile c+2 issued at iter c -> 2-region
// flight), counted s_waitcnt vmcnt(2) (never 0), one raw barrier per iter;
// trig(c+1) + frag reads + MFMA share one region (LDS-BW-bound regime).
// ---------------------------------------------------------------------------
__global__ __launch_bounds__(512) void ker_T(const float* __restrict__ pts,
                                             const float* __restrict__ B) {
    const int q0 = blockIdx.x * 64;
    const int d0 = blockIdx.y * 256;
    const int ks = blockIdx.z;               // n range [ks*4096, +4096)
    const int t  = threadIdx.x;
    const int lane = t & 63, wid = t >> 6;
    const int wm = wid >> 2, wn = wid & 3;

    __shared__ f16 Al[2][128][LDA];   // rows 0..63 cos q, 64..127 sin q (padded)
    __shared__ f16 Bl[3][256][32];    // [d][n] phi-swizzled (gload_lds dest)

    f32x4 acc[4][4];
    #pragma unroll
    for (int a = 0; a < 4; ++a)
        #pragma unroll
        for (int bq = 0; bq < 4; ++bq) acc[a][bq] = (f32x4){0.f,0.f,0.f,0.f};

    // A-trig: qq = t>>3 (0..63), 4 n per iter at nn0=(t&7)*4
    const int qq  = t >> 3;
    const int nn0 = (t & 7) * 4;
    const float b0 = B[q0+qq], b1 = B[PH+q0+qq], b2 = B[2*PH+q0+qq];
    // B gload: lane covers row 32*wid+16*i+(lane>>2), phys slot lane&3.
    // phi(row) = (row + (row>>2)) & 3 == ((lane>>2)&3 + (lane>>4)) & 3.
    const int phiL = (((lane >> 2) & 3) + (lane >> 4)) & 3;
    const size_t bsrc0 = (size_t)(d0 + 32*wid + (lane >> 2))*NPTS
                       + 8 * ((lane & 3) ^ phiL);
    // frag coords
    const int mrow = wm*64 + (lane & 15);
    const int ncol = wn*64 + (lane & 15);
    const int akof = (lane >> 4) * 8;
    // phi(brow) = ((lane&3) + ((lane>>2)&3)) & 3  (nf-independent)
    const int phib = ((lane & 3) + ((lane >> 2) & 3)) & 3;
    const int bkof = ((lane >> 4) ^ phib) * 8;

#define TSB(rg, nb_) do {                                                      \
    gload16(&g_eAt[0][0] + bsrc0 + (size_t)(nb_),              &Bl[rg][32*wid][0]);      \
    gload16(&g_eAt[0][0] + bsrc0 + (size_t)16*NPTS + (size_t)(nb_), &Bl[rg][32*wid+16][0]); \
} while (0)

#define TRIG(ab, nb_) do {                                                     \
    const float* pb = pts + (size_t)((nb_) + nn0)*3;                           \
    const float4 P0 = *(const float4*)(pb);                                    \
    const float4 P1 = *(const float4*)(pb + 4);                                \
    const float4 P2 = *(const float4*)(pb + 8);                                \
    const float xx[4] = {P0.x, P0.w, P1.z, P2.y};                              \
    const float yy[4] = {P0.y, P1.x, P1.w, P2.z};                              \
    const float zz[4] = {P0.z, P1.y, P2.x, P2.w};                              \
    f16x4 vc, vs;                                                              \
    _Pragma("unroll")                                                          \
    for (int u = 0; u < 4; ++u) {                                              \
        float sn, cc; fsincos(xx[u]*b0 + yy[u]*b1 + zz[u]*b2, &sn, &cc);       \
        vc[u] = (f16)cc; vs[u] = (f16)sn;                                      \
    }                                                                          \
    *(f16x4*)&Al[ab][qq][nn0]      = vc;                                       \
    *(f16x4*)&Al[ab][64 + qq][nn0] = vs;                                       \
} while (0)

    const int base = ks*4096;
    // prologue: A tile 0; B tiles 0,1 into rings 0,1
    TRIG(0, base);
    TSB(0, base); TSB(1, base + 32);
    asm volatile("s_waitcnt vmcnt(2)" ::: "memory");   // ring0 done, ring1 in flight
    asm volatile("s_waitcnt lgkmcnt(0)" ::: "memory");
    __builtin_amdgcn_s_barrier();
    __builtin_amdgcn_sched_barrier(0);

    int bcur = 0, bprf = 2;   // ring index of tile c, and of tile c+2
    for (int c = 0; c < 128; ++c) {
        const int nb = base + c*32;
        // trig for tile c+1 -> A[(c+1)&1]  (safe: that buffer's reads drained
        // at the previous barrier); VALU overlaps other waves' MFMA.
        if (c < 127) TRIG((c + 1) & 1, nb + 32);
        // frag reads (tile c) + MFMA
        f16x8 af[4], bf[4];
        #pragma unroll
        for (int mf = 0; mf < 4; ++mf)
            af[mf] = *(const f16x8*)&Al[c & 1][mrow + mf*16][akof];
        #pragma unroll
        for (int nf = 0; nf < 4; ++nf)
            bf[nf] = *(const f16x8*)&Bl[bcur][ncol + nf*16][bkof];
        #pragma unroll
        for (int mf = 0; mf < 4; ++mf)
            #pragma unroll
            for (int nf = 0; nf < 4; ++nf)
                acc[mf][nf] = __builtin_amdgcn_mfma_f32_16x16x32_f16(
                    af[mf], bf[nf], acc[mf][nf], 0, 0, 0);
        // prefetch B for tile c+2 (2-region flight; never drained to 0)
        if (c < 126) TSB(bprf, nb + 64);
        asm volatile("s_waitcnt vmcnt(2)" ::: "memory");   // c+1's loads done; c+2's stay out
        asm volatile("s_waitcnt lgkmcnt(0)" ::: "memory"); // own ds_writes + reads done
        __builtin_amdgcn_s_barrier();
        __builtin_amdgcn_sched_barrier(0);
        bcur = (bcur == 2) ? 0 : bcur + 1;
        bprf = (bprf == 2) ? 0 : bprf + 1;
    }
#undef TSB
#undef TRIG

    // epilogue: wave wm: 0=cos rows, 1=sin rows; D row=(l>>4)*4+j, col=l&15
    #pragma unroll
    for (int mf = 0; mf < 4; ++mf) {
        const int qrow = q0 + mf*16 + (lane >> 4)*4;
        #pragma unroll
        for (int nf = 0; nf < 4; ++nf) {
            const int d = d0 + wn*64 + nf*16 + (lane & 15);
            f16x4 v;
            #pragma unroll
            for (int j = 0; j < 4; ++j) v[j] = (f16)acc[mf][nf][j];
            *(f16x4*)&g_Tt[ks][d][(size_t)wm*PH + qrow] = v;
        }
    }
}

// ---------------------------------------------------------------------------
// Sum 4 T partials -> g_Ts, interleaved [d][2q+cs], LINEAR.
// ---------------------------------------------------------------------------
__global__ __launch_bounds__(256) void ker_tsum() {
    const int u  = blockIdx.x*256 + threadIdx.x;   // 2048 blocks x 256 thr
    const int d  = u >> 10;                        // 0..511
    const int jj = u & 1023;                       // 8-half chunk
    const int q0_ = jj * 4;
    float oc[4] = {0,0,0,0}, os[4] = {0,0,0,0};
    #pragma unroll
    for (int z = 0; z < 4; ++z) {
        const f16x4 a  = *(const f16x4*)&g_Tt[z][d][q0_];
        const f16x4 bs = *(const f16x4*)&g_Tt[z][d][PH + q0_];
        #pragma unroll
        for (int j = 0; j < 4; ++j) { oc[j] += (float)a[j]; os[j] += (float)bs[j]; }
    }
    f16x8 v;
    #pragma unroll
    for (int j = 0; j < 4; ++j) { v[2*j] = (f16)oc[j]; v[2*j+1] = (f16)os[j]; }
    *(f16x8*)&g_Ts[d][jj*8] = v;
}

// ---------------------------------------------------------------------------
// GEMM2: G = eB T. Block: M=128 n, N=256 d, BK=32 interleaved k (=16 q x cs).
// Grid (128,2,2) = 512 blocks. Same R16 ring-3/counted-vmcnt schedule.
// ---------------------------------------------------------------------------
__global__ __launch_bounds__(512) void ker_G(const float* __restrict__ pts,
                                             const float* __restrict__ B) {
    const int n0 = blockIdx.x * 128;
    const int d0 = blockIdx.y * 256;
    const int ks = blockIdx.z;               // ik range [ks*4096, +4096)
    const int t  = threadIdx.x;
    const int lane = t & 63, wid = t >> 6;
    const int wm = wid >> 2, wn = wid & 3;

    __shared__ f16 Al[2][128][LDA];   // [n][ik] padded
    __shared__ f16 Bl[3][256][32];    // [d][ik] phi-swizzled (gload_lds dest)

    f32x4 acc[4][4];
    #pragma unroll
    for (int a = 0; a < 4; ++a)
        #pragma unroll
        for (int bq = 0; bq < 4; ++bq) acc[a][bq] = (f32x4){0.f,0.f,0.f,0.f};

    // A-trig: nn = t>>2 (0..127); ik chunk (t&3)*8 = 4 q per iter
    const int nn  = t >> 2;
    const int ikc = (t & 3) * 8;
    const int qc4 = (t & 3) * 4;
    const float px = pts[(size_t)(n0+nn)*3];
    const float py = pts[(size_t)(n0+nn)*3 + 1];
    const float pz = pts[(size_t)(n0+nn)*3 + 2];
    // B gload source (phi in per-lane address)
    const int phiL = (((lane >> 2) & 3) + (lane >> 4)) & 3;
    const size_t bsrc0 = (size_t)(d0 + 32*wid + (lane >> 2))*(2*PH)
                       + 8 * ((lane & 3) ^ phiL);
    const int mrow = wm*64 + (lane & 15);
    const int ncol = wn*64 + (lane & 15);
    const int akof = (lane >> 4) * 8;
    const int phib = ((lane & 3) + ((lane >> 2) & 3)) & 3;
    const int bkof = ((lane >> 4) ^ phib) * 8;

#define GSB(rg, ikb_) do {                                                     \
    gload16(&g_Ts[0][0] + bsrc0 + (size_t)(ikb_),                 &Bl[rg][32*wid][0]);      \
    gload16(&g_Ts[0][0] + bsrc0 + (size_t)16*(2*PH) + (size_t)(ikb_), &Bl[rg][32*wid+16][0]); \
} while (0)

#define GTRIG(ab, ikb_) do {                                                   \
    const int qg = ((ikb_) >> 1) + qc4;                                        \
    const float4 X0 = *(const float4*)&B[qg];                                  \
    const float4 Y0 = *(const float4*)&B[PH + qg];                             \
    const float4 Z0 = *(const float4*)&B[2*PH + qg];                           \
    const float bx[4] = {X0.x, X0.y, X0.z, X0.w};                              \
    const float by[4] = {Y0.x, Y0.y, Y0.z, Y0.w};                              \
    const float bz[4] = {Z0.x, Z0.y, Z0.z, Z0.w};                              \
    f16x8 vv;                                                                  \
    _Pragma("unroll")                                                          \
    for (int u = 0; u < 4; ++u) {                                              \
        float sn, cc; fsincos(px*bx[u] + py*by[u] + pz*bz[u], &sn, &cc);       \
        vv[2*u] = (f16)cc; vv[2*u+1] = (f16)sn;                                \
    }                                                                          \
    *(f16x8*)&Al[ab][nn][ikc] = vv;                                            \
} while (0)

    const int base = ks*4096;
    GTRIG(0, base);
    GSB(0, base); GSB(1, base + 32);
    asm volatile("s_waitcnt vmcnt(2)" ::: "memory");
    asm volatile("s_waitcnt lgkmcnt(0)" ::: "memory");
    __builtin_amdgcn_s_barrier();
    __builtin_amdgcn_sched_barrier(0);

    int bcur = 0, bprf = 2;
    for (int c = 0; c < 128; ++c) {
        const int ikb = base + c*32;
        if (c < 127) GTRIG((c + 1) & 1, ikb + 32);
        f16x8 af[4], bf[4];
        #pragma unroll
        for (int mf = 0; mf < 4; ++mf)
            af[mf] = *(const f16x8*)&Al[c & 1][mrow + mf*16][akof];
        #pragma unroll
        for (int nf = 0; nf < 4; ++nf)
            bf[nf] = *(const f16x8*)&Bl[bcur][ncol + nf*16][bkof];
        #pragma unroll
        for (int mf = 0; mf < 4; ++mf)
            #pragma unroll
            for (int nf = 0; nf < 4; ++nf)
                acc[mf][nf] = __builtin_amdgcn_mfma_f32_16x16x32_f16(
                    af[mf], bf[nf], acc[mf][nf], 0, 0, 0);
        if (c < 126) GSB(bprf, ikb + 64);
        asm volatile("s_waitcnt vmcnt(2)" ::: "memory");
        asm volatile("s_waitcnt lgkmcnt(0)" ::: "memory");
        __builtin_amdgcn_s_barrier();
        __builtin_amdgcn_sched_barrier(0);
        bcur = (bcur == 2) ? 0 : bcur + 1;
        bprf = (bprf == 2) ? 0 : bprf + 1;
    }
#undef GSB
#undef GTRIG

    // epilogue -> g_G[ks][n][d] fp32
    #pragma unroll
    for (int mf = 0; mf < 4; ++mf) {
        const int nbase = n0 + wm*64 + mf*16 + (lane >> 4)*4;
        #pragma unroll
        for (int nf = 0; nf < 4; ++nf) {
            const int d = d0 + wn*64 + nf*16 + (lane & 15);
            #pragma unroll
            for (int j = 0; j < 4; ++j)
                g_G[ks][nbase + j][d] = acc[mf][nf][j];
        }
    }
}

// ---------------------------------------------------------------------------
// Epilogue: Gc = (Gr+i*Gi)*conj(e^{i alpha}) (|e^{ia}|=1, divide==conj-mult;
// rotation preserves row norm -> scale = 16/||G row||). Output = REAL part.
// ---------------------------------------------------------------------------
__global__ __launch_bounds__(256) void ker_fin(const float* __restrict__ pts,
                                               const float* __restrict__ A,
                                               float* __restrict__ out) {
    const int n = blockIdx.x;
    const int k = threadIdx.x;  // 0..255
    const float p0 = pts[(size_t)n*3], p1 = pts[(size_t)n*3+1], p2 = pts[(size_t)n*3+2];
    const float alp = p0*A[k] + p1*A[DH + k] + p2*A[2*DH + k];
    float sa, ca; fsincos(alp, &sa, &ca);
    const float Gr = g_G[0][n][k]      + g_G[1][n][k];
    const float Gi = g_G[0][n][DH + k] + g_G[1][n][DH + k];
    const float Re = Gr*ca + Gi*sa;
    float nr = Gr*Gr + Gi*Gi;
    #pragma unroll
    for (int off = 32; off > 0; off >>= 1) nr += __shfl_down(nr, off, 64);
    __shared__ float wsum[4];
    if ((k & 63) == 0) wsum[k >> 6] = nr;
    __syncthreads();
    const float total = wsum[0] + wsum[1] + wsum[2] + wsum[3];
    const float scale = 16.0f * rsqrtf(total);
    out[(size_t)n*DH + k] = Re * scale;
}

extern "C" void kernel_launch(void* const* d_in, const int* in_sizes, int n_in,
                              void* d_out, int out_size, void* d_ws, size_t ws_size,
                              hipStream_t stream) {
    const float* pts = (const float*)d_in[0];
    const float* A   = (const float*)d_in[1];
    const float* B   = (const float*)d_in[2];
    float* out = (float*)d_out;
    (void)d_ws; (void)ws_size; (void)out_size;

    ker_pre <<<256, 256, 0, stream>>>(pts, A);
    ker_T   <<<dim3(64, 2, 4), 512, 0, stream>>>(pts, B);
    ker_tsum<<<2048, 256, 0, stream>>>();
    ker_G   <<<dim3(128, 2, 2), 512, 0, stream>>>(pts, B);
    ker_fin <<<16384, 256, 0, stream>>>(pts, A, out);
}